// Round 2
// baseline (438.140 us; speedup 1.0000x reference)
//
#include <hip/hip_runtime.h>
#include <hip/hip_bf16.h>
#include <math.h>

#define BATCH 16
#define NN 2048
#define FF 128
#define CC 32
#define HID 512
#define QM 512                 // m-columns per staged hT slice (quarter of NN)
#define LSTR 520               // 512 + 8 pad (1040 B LDS row stride)
#define KS1 128                // agg1 K-step (columns per staged A tile)

typedef float v4f __attribute__((ext_vector_type(4)));
typedef float v2f __attribute__((ext_vector_type(2)));
typedef short short8 __attribute__((ext_vector_type(8)));
typedef short s4v __attribute__((ext_vector_type(4)));

__device__ __forceinline__ unsigned short f2bf(float f) {
  unsigned u = __float_as_uint(f);
  u += 0x7fffu + ((u >> 16) & 1u);
  return (unsigned short)(u >> 16);
}

__device__ __forceinline__ float elu1(float x) {
  return x > 0.f ? x : expm1f(x);
}

// ---------------------------------------------------------------------------
// k_xw1: hT1[b][c][n] = bf16( x[row][0:128] @ w1[128][32] )
// ---------------------------------------------------------------------------
__global__ __launch_bounds__(256)
void k_xw1(const float* __restrict__ src, const float* __restrict__ w,
           unsigned short* __restrict__ outT) {
  int t = threadIdx.x;
  int wv = t >> 6, l = t & 63, lo = l & 15, q = l >> 4;
  int rowt = blockIdx.x * 4 + wv;
  long row = (long)rowt * 16 + lo;

  short8 wf[FF / 32][2];
#pragma unroll
  for (int kc = 0; kc < FF / 32; ++kc)
#pragma unroll
    for (int h = 0; h < 2; ++h) {
      short8 f;
#pragma unroll
      for (int j = 0; j < 8; ++j)
        f[j] = (short)f2bf(w[(kc * 32 + q * 8 + j) * CC + h * 16 + lo]);
      wf[kc][h] = f;
    }

  v4f acc0 = {0.f, 0.f, 0.f, 0.f}, acc1 = {0.f, 0.f, 0.f, 0.f};
#pragma unroll
  for (int kc = 0; kc < FF / 32; ++kc) {
    const float* sp = src + row * FF + kc * 32 + q * 8;
    float4 a0 = *(const float4*)sp;
    float4 a1 = *(const float4*)(sp + 4);
    short8 af;
    af[0] = (short)f2bf(a0.x); af[1] = (short)f2bf(a0.y);
    af[2] = (short)f2bf(a0.z); af[3] = (short)f2bf(a0.w);
    af[4] = (short)f2bf(a1.x); af[5] = (short)f2bf(a1.y);
    af[6] = (short)f2bf(a1.z); af[7] = (short)f2bf(a1.w);
    acc0 = __builtin_amdgcn_mfma_f32_16x16x32_bf16(af, wf[kc][0], acc0, 0, 0, 0);
    acc1 = __builtin_amdgcn_mfma_f32_16x16x32_bf16(af, wf[kc][1], acc1, 0, 0, 0);
  }

  int b = rowt >> 7;
  int nbase = (rowt & 127) * 16;
#pragma unroll
  for (int r = 0; r < 4; ++r) {
    int n = nbase + q * 4 + r;
    outT[((long)b * CC + lo) * NN + n] = f2bf(acc0[r]);
    outT[((long)b * CC + 16 + lo) * NN + n] = f2bf(acc1[r]);
  }
}

// ---------------------------------------------------------------------------
// k_agg1f (R1): FULL-K aggregation. Each block owns 64 n-rows, loops all
// m=0..2047 in 16 steps of 128 (hT slice re-staged per quarter). Emits
// afp8 = e4m3(a*1024) at stage time, and writes h1 = elu(sum + b1) as f32
// [B][N][32] (4.2 MB) -- the 67 MB quarter-partial round trip is GONE.
// MFMA accumulation order identical to the old quarter-split ((q0+q1)+q2)+q3.
// grid = 16b x 32rt = 512 blocks x 256 thr; LDS 66 KB -> 2 blocks/CU (exact).
// ---------------------------------------------------------------------------
__global__ __launch_bounds__(256, 2)
void k_agg1f(const float* __restrict__ a, unsigned char* __restrict__ afp8,
             const unsigned short* __restrict__ hT, const float* __restrict__ b1,
             float* __restrict__ h1) {
  __shared__ __attribute__((aligned(16))) unsigned short hs[CC * LSTR];
  __shared__ __attribute__((aligned(16))) unsigned short at[2][64 * KS1];

  int t = threadIdx.x;
  int bid = blockIdx.x;
  int rt = bid & 31, b = bid >> 5;
  int n0 = rt * 64;

  // stage-thread geometry: r0 in 0..7, chunk in 0..31 (per row-step: 32x16 B)
  int r0 = t >> 5, chunk = t & 31;
  const float* ga = a + ((long)(b * NN + n0 + r0)) * NN + chunk * 4;
  unsigned char* gao = afp8 + ((long)(b * NN + n0 + r0)) * NN + chunk * 4;
  int swb = r0 * 256 + ((chunk * 8) ^ (r0 << 4));   // swizzled LDS byte base

  float4 ar[8];
  const float sc = 1024.f;

  // ---- prologue: issue A loads for step 0 (long latency first)
#pragma unroll
  for (int j = 0; j < 8; ++j)
    ar[j] = *(const float4*)(ga + (long)j * 8 * NN);

  // stage hT slice for qm=0 (1-KB contiguous bursts, L2/L3-resident)
#pragma unroll
  for (int i = 0; i < 8; ++i) {
    int jj = i * 256 + t;
    int c = jj >> 6, off = (jj & 63) * 8;
    *(uint4*)&hs[c * LSTR + off] =
        *(const uint4*)(hT + ((long)b * CC + c) * NN + off);
  }

  // writeback step 0 into buf0 + fp8 emit
#pragma unroll
  for (int j = 0; j < 8; ++j) {
    char* lp = (char*)&at[0][0] + swb + j * 2048;
    s4v bv;
    bv[0] = (short)f2bf(ar[j].x); bv[1] = (short)f2bf(ar[j].y);
    bv[2] = (short)f2bf(ar[j].z); bv[3] = (short)f2bf(ar[j].w);
    *(s4v*)lp = bv;
    int w0 = __builtin_amdgcn_cvt_pk_fp8_f32(ar[j].x * sc, ar[j].y * sc, 0, false);
    w0 = __builtin_amdgcn_cvt_pk_fp8_f32(ar[j].z * sc, ar[j].w * sc, w0, true);
    *(int*)(gao + (long)j * 8 * NN) = w0;
  }
  __syncthreads();

  // compute-thread geometry
  int l = t & 63, wv = t >> 6, lo = l & 15, q = l >> 4;
  int lrow = wv * 16 + lo;
  const unsigned short* h0 = &hs[lo * LSTR + q * 8];

  v4f acc0 = {0.f, 0.f, 0.f, 0.f}, acc1 = {0.f, 0.f, 0.f, 0.f};

  for (int step = 0; step < 16; ++step) {
    // T14 split: issue next-step global loads before compute
    if (step < 15) {
#pragma unroll
      for (int j = 0; j < 8; ++j)
        ar[j] = *(const float4*)(ga + (long)j * 8 * NN + (step + 1) * KS1);
    }
    const char* ab = (const char*)at + (step & 1) * (64 * KS1 * 2);
    int mloc = (step & 3) * KS1;          // column offset within current hs slice
#pragma unroll
    for (int kk = 0; kk < 4; ++kk) {
      short8 af = *(const short8*)(ab + lrow * 256 +
                                   ((q * 16 + kk * 64) ^ ((lo & 7) << 4)));
      int m = mloc + kk * 32;
      short8 b0 = *(const short8*)(h0 + m);
      short8 b1v = *(const short8*)(h0 + 16 * LSTR + m);
      acc0 = __builtin_amdgcn_mfma_f32_16x16x32_bf16(af, b0, acc0, 0, 0, 0);
      acc1 = __builtin_amdgcn_mfma_f32_16x16x32_bf16(af, b1v, acc1, 0, 0, 0);
    }
    if (step < 15) {
      char* lb = (char*)&at[(step + 1) & 1][0];
#pragma unroll
      for (int j = 0; j < 8; ++j) {
        char* lp = lb + swb + j * 2048;
        s4v bv;
        bv[0] = (short)f2bf(ar[j].x); bv[1] = (short)f2bf(ar[j].y);
        bv[2] = (short)f2bf(ar[j].z); bv[3] = (short)f2bf(ar[j].w);
        *(s4v*)lp = bv;
        int w0 = __builtin_amdgcn_cvt_pk_fp8_f32(ar[j].x * sc, ar[j].y * sc, 0, false);
        w0 = __builtin_amdgcn_cvt_pk_fp8_f32(ar[j].z * sc, ar[j].w * sc, w0, true);
        *(int*)(gao + (long)j * 8 * NN + (step + 1) * KS1) = w0;
      }
      __syncthreads();
      if ((step & 3) == 3) {
        // qm boundary: all waves past their hs reads (barrier above) -> restage
        int qm = (step >> 2) + 1;
#pragma unroll
        for (int i = 0; i < 8; ++i) {
          int jj = i * 256 + t;
          int c = jj >> 6, off = (jj & 63) * 8;
          *(uint4*)&hs[c * LSTR + off] =
              *(const uint4*)(hT + ((long)b * CC + c) * NN + qm * QM + off);
        }
        __syncthreads();
      }
    }
  }

  // epilogue: h1 = elu(acc + b1) -- full-K sum, bit-identical order to old path
  float* hp = h1 + (long)b * NN * CC;
#pragma unroll
  for (int r = 0; r < 4; ++r) {
    int n = n0 + wv * 16 + q * 4 + r;
    hp[(long)n * CC + lo] = elu1(acc0[r] + b1[lo]);
    hp[(long)n * CC + 16 + lo] = elu1(acc1[r] + b1[16 + lo]);
  }
}

// ---------------------------------------------------------------------------
// k_xw2 (R1): hT2[b][c][n] = bf16( 2^-10 * h1[row] @ w2 ); h1 already has elu.
// ---------------------------------------------------------------------------
__global__ __launch_bounds__(256)
void k_xw2(const float* __restrict__ h1, const float* __restrict__ w2,
           unsigned short* __restrict__ outT) {
  int t = threadIdx.x;
  int wv = t >> 6, l = t & 63, lo = l & 15, q = l >> 4;
  int rowt = blockIdx.x * 4 + wv;
  long row = (long)rowt * 16 + lo;

  short8 wf[2];
#pragma unroll
  for (int h = 0; h < 2; ++h) {
    short8 f;
#pragma unroll
    for (int j = 0; j < 8; ++j)
      f[j] = (short)f2bf(w2[(q * 8 + j) * CC + h * 16 + lo]);
    wf[h] = f;
  }

  const float* p = h1 + row * CC + q * 8;
  float4 u0 = *(const float4*)p;
  float4 u1 = *(const float4*)(p + 4);
  short8 af;
  af[0] = (short)f2bf(u0.x); af[1] = (short)f2bf(u0.y);
  af[2] = (short)f2bf(u0.z); af[3] = (short)f2bf(u0.w);
  af[4] = (short)f2bf(u1.x); af[5] = (short)f2bf(u1.y);
  af[6] = (short)f2bf(u1.z); af[7] = (short)f2bf(u1.w);

  v4f acc0 = {0.f, 0.f, 0.f, 0.f}, acc1 = {0.f, 0.f, 0.f, 0.f};
  acc0 = __builtin_amdgcn_mfma_f32_16x16x32_bf16(af, wf[0], acc0, 0, 0, 0);
  acc1 = __builtin_amdgcn_mfma_f32_16x16x32_bf16(af, wf[1], acc1, 0, 0, 0);

  const float inv = 1.f / 1024.f;
  int b = rowt >> 7;
  int nbase = (rowt & 127) * 16;
#pragma unroll
  for (int r = 0; r < 4; ++r) {
    int n = nbase + q * 4 + r;
    outT[((long)b * CC + lo) * NN + n] = f2bf(acc0[r] * inv);
    outT[((long)b * CC + 16 + lo) * NN + n] = f2bf(acc1[r] * inv);
  }
}

// ---------------------------------------------------------------------------
// k_agg2f (R1): FULL-K aggregation over afp8 + FUSED POOL. Each block owns
// 64 n-rows; per quarter: stage 32 KB fp8 A-tile + 33 KB hT2 slice (prefetch
// A into regs during previous quarter's MFMAs), 32 MFMAs between barriers.
// Epilogue: elu(acc + b2), in-register pool reduce (shfl over q, LDS over
// waves) -> pp2[b][rt][32]. h2 NEVER touches HBM (saves 134 MB round trip).
// grid = 512 x 256; LDS 66 KB -> 2 blocks/CU (exact).
// ---------------------------------------------------------------------------
__global__ __launch_bounds__(256, 2)
void k_agg2f(const unsigned char* __restrict__ afp8,
             const unsigned short* __restrict__ hT, const float* __restrict__ b2,
             float* __restrict__ pp2) {
  __shared__ __attribute__((aligned(16))) unsigned short hs[CC * LSTR];
  __shared__ __attribute__((aligned(16))) unsigned char a2[64 * QM];
  __shared__ float red[4][CC];

  int t = threadIdx.x;
  int bid = blockIdx.x;
  int rt = bid & 31, b = bid >> 5;
  int n0 = rt * 64;

  int r0 = t >> 5, chunk = t & 31;
  const unsigned char* ga = afp8 + ((long)(b * NN + n0 + r0)) * NN + chunk * 16;
  char* lw = (char*)a2 + r0 * 512 + ((chunk * 16) ^ (r0 << 4));

  uint4 arr[8];
  // prologue: qm=0 A-tile + hs
#pragma unroll
  for (int j = 0; j < 8; ++j)
    arr[j] = *(const uint4*)(ga + (long)j * 8 * NN);
#pragma unroll
  for (int i = 0; i < 8; ++i) {
    int jj = i * 256 + t;
    int c = jj >> 6, off = (jj & 63) * 8;
    *(uint4*)&hs[c * LSTR + off] =
        *(const uint4*)(hT + ((long)b * CC + c) * NN + off);
  }
#pragma unroll
  for (int j = 0; j < 8; ++j)
    *(uint4*)(lw + j * 4096) = arr[j];
  __syncthreads();

  int l = t & 63, wv = t >> 6, lo = l & 15, q = l >> 4;
  int lrow = wv * 16 + lo;
  const unsigned short* h0 = &hs[lo * LSTR + q * 8];
  const char* ab = (const char*)a2;

  v4f acc0 = {0.f, 0.f, 0.f, 0.f}, acc1 = {0.f, 0.f, 0.f, 0.f};

  for (int qm = 0; qm < 4; ++qm) {
    if (qm < 3) {
#pragma unroll
      for (int j = 0; j < 8; ++j)
        arr[j] = *(const uint4*)(ga + (long)j * 8 * NN + (qm + 1) * QM);
    }
#pragma unroll
    for (int kk = 0; kk < 16; ++kk) {
      int2 av = *(const int2*)(ab + lrow * 512 +
                               ((q * 8 + kk * 32) ^ ((lo & 7) << 4)));
      v2f f01 = __builtin_amdgcn_cvt_pk_f32_fp8(av.x, false);
      v2f f23 = __builtin_amdgcn_cvt_pk_f32_fp8(av.x, true);
      v2f f45 = __builtin_amdgcn_cvt_pk_f32_fp8(av.y, false);
      v2f f67 = __builtin_amdgcn_cvt_pk_f32_fp8(av.y, true);
      short8 af;
      af[0] = (short)f2bf(f01.x); af[1] = (short)f2bf(f01.y);
      af[2] = (short)f2bf(f23.x); af[3] = (short)f2bf(f23.y);
      af[4] = (short)f2bf(f45.x); af[5] = (short)f2bf(f45.y);
      af[6] = (short)f2bf(f67.x); af[7] = (short)f2bf(f67.y);
      int m = kk * 32;
      short8 b0 = *(const short8*)(h0 + m);
      short8 b1v = *(const short8*)(h0 + 16 * LSTR + m);
      acc0 = __builtin_amdgcn_mfma_f32_16x16x32_bf16(af, b0, acc0, 0, 0, 0);
      acc1 = __builtin_amdgcn_mfma_f32_16x16x32_bf16(af, b1v, acc1, 0, 0, 0);
    }
    if (qm < 3) {
      __syncthreads();
#pragma unroll
      for (int j = 0; j < 8; ++j)
        *(uint4*)(lw + j * 4096) = arr[j];
      int nq = qm + 1;
#pragma unroll
      for (int i = 0; i < 8; ++i) {
        int jj = i * 256 + t;
        int c = jj >> 6, off = (jj & 63) * 8;
        *(uint4*)&hs[c * LSTR + off] =
            *(const uint4*)(hT + ((long)b * CC + c) * NN + nq * QM + off);
      }
      __syncthreads();
    }
  }

  // epilogue: elu + fused global-sum-pool partial for this block's 64 rows
  float s0 = 0.f, s1 = 0.f;
  float bc0 = b2[lo], bc1 = b2[16 + lo];
#pragma unroll
  for (int r = 0; r < 4; ++r) {
    s0 += elu1(acc0[r] + bc0);
    s1 += elu1(acc1[r] + bc1);
  }
  // reduce over q (lanes differing in bits 4,5)
  s0 += __shfl_xor(s0, 16); s0 += __shfl_xor(s0, 32);
  s1 += __shfl_xor(s1, 16); s1 += __shfl_xor(s1, 32);
  if (l < 16) {
    red[wv][lo] = s0;
    red[wv][16 + lo] = s1;
  }
  __syncthreads();
  if (t < CC) {
    float p = red[0][t] + red[1][t] + red[2][t] + red[3][t];
    pp2[((long)b * 32 + rt) * CC + t] = p;
  }
}

// ---------------------------------------------------------------------------
// k5: out[b] = sigmoid( relu((sum_rt pp2)@wf1 + bf1) @ wf2 + bf2 )
// ---------------------------------------------------------------------------
__global__ __launch_bounds__(512)
void k5_mlp(const float* __restrict__ pp2, const float* __restrict__ wf1,
            const float* __restrict__ bf1, const float* __restrict__ wf2,
            const float* __restrict__ bf2, float* __restrict__ out) {
  __shared__ float red[HID];
  __shared__ float ps[CC];
  int b = blockIdx.x, j = threadIdx.x;
  if (j < CC) {
    float s = 0.f;
#pragma unroll
    for (int rt = 0; rt < 32; ++rt) s += pp2[((long)b * 32 + rt) * CC + j];
    ps[j] = s;
  }
  __syncthreads();
  float acc = bf1[j];
#pragma unroll
  for (int c = 0; c < CC; ++c) acc += ps[c] * wf1[c * HID + j];
  red[j] = fmaxf(acc, 0.f) * wf2[j];
  __syncthreads();
  for (int s = HID / 2; s > 0; s >>= 1) {
    if (j < s) red[j] += red[j + s];
    __syncthreads();
  }
  if (j == 0) out[b] = 1.f / (1.f + expf(-(red[0] + bf2[0])));
}

// ---------------------------------------------------------------------------
extern "C" void kernel_launch(void* const* d_in, const int* in_sizes, int n_in,
                              void* d_out, int out_size, void* d_ws, size_t ws_size,
                              hipStream_t stream) {
  const float* x   = (const float*)d_in[0];
  const float* a   = (const float*)d_in[1];
  const float* w1  = (const float*)d_in[2];
  const float* b1  = (const float*)d_in[3];
  const float* w2  = (const float*)d_in[4];
  const float* b2  = (const float*)d_in[5];
  const float* wf1 = (const float*)d_in[6];
  const float* bf1 = (const float*)d_in[7];
  const float* wf2 = (const float*)d_in[8];
  const float* bf2 = (const float*)d_in[9];
  float* out = (float*)d_out;

  char* ws = (char*)d_ws;
  unsigned char*  afp8 = (unsigned char*)ws;                   // 64 MB fp8 a
  unsigned short* hT1  = (unsigned short*)(ws + 0x4000000UL);  // 2 MB
  unsigned short* hT2  = (unsigned short*)(ws + 0x4200000UL);  // 2 MB
  float* h1  = (float*)(ws + 0x4400000UL);                     // 4.2 MB
  float* pp2 = (float*)(ws + 0x4800000UL);                     // 64 KB

  k_xw1<<<512, 256, 0, stream>>>(x, w1, hT1);
  k_agg1f<<<512, 256, 0, stream>>>(a, afp8, hT1, b1, h1);
  k_xw2<<<512, 256, 0, stream>>>(h1, w2, hT2);
  k_agg2f<<<512, 256, 0, stream>>>(afp8, hT2, b2, pp2);
  k5_mlp<<<BATCH, HID, 0, stream>>>(pp2, wf1, bf1, wf2, bf2, out);
}